// Round 1
// baseline (768.098 us; speedup 1.0000x reference)
//
#include <hip/hip_runtime.h>

#define B 8
#define H 4096
#define NH 32
#define HD 128
#define P 2047
#define T 2048          // P + 1 (cache + appended token)
#define HQKV 12288      // 3*H

// ---------------------------------------------------------------------------
// Kernel 0: seed qkv workspace with bqkv and d_out with bproj so the k-split
// GEMMs can atomicAdd into them. Re-runs every call (ws/out are re-poisoned).
// ---------------------------------------------------------------------------
__global__ __launch_bounds__(256) void init_bias_kernel(
    const float* __restrict__ bqkv, const float* __restrict__ bproj,
    float* __restrict__ qkv, float* __restrict__ out)
{
    int i = blockIdx.x * 256 + threadIdx.x;
    if (i < B * HQKV) {
        qkv[i] = bqkv[i % HQKV];
    } else {
        int j = i - B * HQKV;
        if (j < B * H) out[j] = bproj[j & (H - 1)];
    }
}

// ---------------------------------------------------------------------------
// Kernel 1: qkv = x @ Wqkv  (+bias already seeded).
// Wqkv rows streamed coalesced: lane -> 4 consecutive cols (float4, 1KB/wave).
// x chunk addresses are wave-uniform -> scalar-cache loads.
// Grid = 12 col-blocks (1024 cols each) x 32 k-chunks (128 rows each) = 384.
// ---------------------------------------------------------------------------
#define QKV_CB 12
#define QKV_KSPLIT 32
#define QKV_KCHUNK 128   // H / QKV_KSPLIT

__global__ __launch_bounds__(256) void qkv_gemm_kernel(
    const float* __restrict__ x, const float* __restrict__ W,
    float* __restrict__ qkv)
{
    const int cb = blockIdx.x % QKV_CB;
    const int kc = blockIdx.x / QKV_CB;
    const int c0 = cb * 1024 + threadIdx.x * 4;
    const int k0 = kc * QKV_KCHUNK;

    float4 acc[B];
#pragma unroll
    for (int b = 0; b < B; ++b) acc[b] = make_float4(0.f, 0.f, 0.f, 0.f);

    const float* wp = W + (size_t)k0 * HQKV + c0;
    const float* xp = x + k0;

    for (int k = 0; k < QKV_KCHUNK; k += 4) {
        float4 w0 = *(const float4*)(wp + (size_t)(k + 0) * HQKV);
        float4 w1 = *(const float4*)(wp + (size_t)(k + 1) * HQKV);
        float4 w2 = *(const float4*)(wp + (size_t)(k + 2) * HQKV);
        float4 w3 = *(const float4*)(wp + (size_t)(k + 3) * HQKV);
#pragma unroll
        for (int b = 0; b < B; ++b) {
            float4 xv = *(const float4*)(xp + b * H + k);  // wave-uniform
            acc[b].x += xv.x * w0.x + xv.y * w1.x + xv.z * w2.x + xv.w * w3.x;
            acc[b].y += xv.x * w0.y + xv.y * w1.y + xv.z * w2.y + xv.w * w3.y;
            acc[b].z += xv.x * w0.z + xv.y * w1.z + xv.z * w2.z + xv.w * w3.z;
            acc[b].w += xv.x * w0.w + xv.y * w1.w + xv.z * w2.w + xv.w * w3.w;
        }
    }
#pragma unroll
    for (int b = 0; b < B; ++b) {
        float* q = qkv + b * HQKV + c0;
        atomicAdd(q + 0, acc[b].x);
        atomicAdd(q + 1, acc[b].y);
        atomicAdd(q + 2, acc[b].z);
        atomicAdd(q + 3, acc[b].w);
    }
}

// ---------------------------------------------------------------------------
// Kernel 2: attention. One block per (b,h), 16 waves, lane holds float2 of
// the 128-dim head. Phase 1: scores into LDS (shfl-reduce dot per t).
// Phase 2: softmax-weighted sum of V. New token (t=P) comes from qkv ws.
// ---------------------------------------------------------------------------
#define AT_NW 16

__global__ __launch_bounds__(1024) void attn_kernel(
    const float* __restrict__ cache_k, const float* __restrict__ cache_v,
    const float* __restrict__ qkv, float* __restrict__ attn_out)
{
    __shared__ float sc[T];            // 8 KB scores -> probabilities
    __shared__ float wred[AT_NW];
    __shared__ float ored[AT_NW][HD];  // 8 KB cross-wave O reduction
    __shared__ float s_stats[2];       // max, sum

    const int b    = blockIdx.x >> 5;
    const int h    = blockIdx.x & 31;
    const int tid  = threadIdx.x;
    const int wave = tid >> 6;
    const int lane = tid & 63;
    const float scale = 0.08838834764831845f;  // 1/sqrt(128)

    const float* qp = qkv + b * HQKV + h * HD;
    float2 q2 = *(const float2*)(qp + 2 * lane);

    const float* kbase = cache_k + (size_t)b * NH * HD + h * HD + 2 * lane;
    const float* knew  = qkv + b * HQKV + H + h * HD + 2 * lane;

    // ---- phase 1: scores ----
#pragma unroll 2
    for (int t = wave; t < T; t += AT_NW) {   // t is wave-uniform: no divergence
        const float* kp = (t < P) ? (kbase + (size_t)t * (B * NH * HD)) : knew;
        float2 k2 = *(const float2*)kp;
        float ps = q2.x * k2.x + q2.y * k2.y;
#pragma unroll
        for (int off = 32; off >= 1; off >>= 1) ps += __shfl_xor(ps, off);
        if (lane == 0) sc[t] = ps * scale;
    }
    __syncthreads();

    // ---- softmax stats ----
    float m = -1e30f;
    for (int i = tid; i < T; i += 1024) m = fmaxf(m, sc[i]);
#pragma unroll
    for (int off = 32; off >= 1; off >>= 1) m = fmaxf(m, __shfl_xor(m, off));
    if (lane == 0) wred[wave] = m;
    __syncthreads();
    if (tid == 0) {
        float mm = wred[0];
#pragma unroll
        for (int w = 1; w < AT_NW; ++w) mm = fmaxf(mm, wred[w]);
        s_stats[0] = mm;
    }
    __syncthreads();
    const float gm = s_stats[0];
    float ls = 0.f;
    for (int i = tid; i < T; i += 1024) {
        float p = __expf(sc[i] - gm);
        sc[i] = p;
        ls += p;
    }
#pragma unroll
    for (int off = 32; off >= 1; off >>= 1) ls += __shfl_xor(ls, off);
    if (lane == 0) wred[wave] = ls;
    __syncthreads();
    if (tid == 0) {
        float ss = 0.f;
#pragma unroll
        for (int w = 0; w < AT_NW; ++w) ss += wred[w];
        s_stats[1] = ss;
    }
    __syncthreads();
    const float inv_l = 1.0f / s_stats[1];

    // ---- phase 2: O = sum_t p_t * v_t ----
    const float* vbase = cache_v + (size_t)b * NH * HD + h * HD + 2 * lane;
    const float* vnew  = qkv + b * HQKV + 2 * H + h * HD + 2 * lane;
    float2 o2 = make_float2(0.f, 0.f);
#pragma unroll 2
    for (int t = wave; t < T; t += AT_NW) {
        const float* vp = (t < P) ? (vbase + (size_t)t * (B * NH * HD)) : vnew;
        float2 v2 = *(const float2*)vp;
        float p = sc[t];                       // LDS broadcast
        o2.x += p * v2.x;
        o2.y += p * v2.y;
    }
    *(float2*)&ored[wave][2 * lane] = o2;
    __syncthreads();
    if (tid < HD) {
        float s = 0.f;
#pragma unroll
        for (int w = 0; w < AT_NW; ++w) s += ored[w][tid];
        attn_out[b * H + h * HD + tid] = s * inv_l;
    }
}

// ---------------------------------------------------------------------------
// Kernel 3: out = attn_out @ Wproj (+bias already seeded in d_out).
// Grid = 4 col-blocks x 64 k-chunks (64 rows) = 256 blocks.
// ---------------------------------------------------------------------------
#define PR_CB 4
#define PR_KSPLIT 64
#define PR_KCHUNK 64     // H / PR_KSPLIT

__global__ __launch_bounds__(256) void proj_gemm_kernel(
    const float* __restrict__ attn, const float* __restrict__ W,
    float* __restrict__ out)
{
    const int cb = blockIdx.x % PR_CB;
    const int kc = blockIdx.x / PR_CB;
    const int c0 = cb * 1024 + threadIdx.x * 4;
    const int k0 = kc * PR_KCHUNK;

    float4 acc[B];
#pragma unroll
    for (int b = 0; b < B; ++b) acc[b] = make_float4(0.f, 0.f, 0.f, 0.f);

    const float* wp = W + (size_t)k0 * H + c0;
    const float* xp = attn + k0;

    for (int k = 0; k < PR_KCHUNK; k += 4) {
        float4 w0 = *(const float4*)(wp + (size_t)(k + 0) * H);
        float4 w1 = *(const float4*)(wp + (size_t)(k + 1) * H);
        float4 w2 = *(const float4*)(wp + (size_t)(k + 2) * H);
        float4 w3 = *(const float4*)(wp + (size_t)(k + 3) * H);
#pragma unroll
        for (int b = 0; b < B; ++b) {
            float4 xv = *(const float4*)(xp + b * H + k);  // wave-uniform
            acc[b].x += xv.x * w0.x + xv.y * w1.x + xv.z * w2.x + xv.w * w3.x;
            acc[b].y += xv.x * w0.y + xv.y * w1.y + xv.z * w2.y + xv.w * w3.y;
            acc[b].z += xv.x * w0.z + xv.y * w1.z + xv.z * w2.z + xv.w * w3.z;
            acc[b].w += xv.x * w0.w + xv.y * w1.w + xv.z * w2.w + xv.w * w3.w;
        }
    }
#pragma unroll
    for (int b = 0; b < B; ++b) {
        float* o = out + b * H + c0;
        atomicAdd(o + 0, acc[b].x);
        atomicAdd(o + 1, acc[b].y);
        atomicAdd(o + 2, acc[b].z);
        atomicAdd(o + 3, acc[b].w);
    }
}

// ---------------------------------------------------------------------------
extern "C" void kernel_launch(void* const* d_in, const int* in_sizes, int n_in,
                              void* d_out, int out_size, void* d_ws, size_t ws_size,
                              hipStream_t stream)
{
    const float* x       = (const float*)d_in[0];
    const float* cache_k = (const float*)d_in[1];
    const float* cache_v = (const float*)d_in[2];
    const float* Wqkv    = (const float*)d_in[3];
    const float* bqkv    = (const float*)d_in[4];
    const float* Wproj   = (const float*)d_in[5];
    const float* bproj   = (const float*)d_in[6];
    // d_in[7] = cache_pos (always P; unused by the reference math)

    float* qkv      = (float*)d_ws;           // B*HQKV floats
    float* attn_out = qkv + B * HQKV;         // B*H floats
    float* out      = (float*)d_out;

    hipLaunchKernelGGL(init_bias_kernel,
                       dim3((B * HQKV + B * H) / 256), dim3(256), 0, stream,
                       bqkv, bproj, qkv, out);
    hipLaunchKernelGGL(qkv_gemm_kernel,
                       dim3(QKV_CB * QKV_KSPLIT), dim3(256), 0, stream,
                       x, Wqkv, qkv);
    hipLaunchKernelGGL(attn_kernel,
                       dim3(B * NH), dim3(1024), 0, stream,
                       cache_k, cache_v, qkv, attn_out);
    hipLaunchKernelGGL(proj_gemm_kernel,
                       dim3(PR_CB * PR_KSPLIT), dim3(256), 0, stream,
                       attn_out, Wproj, out);
}